// Round 3
// baseline (336.838 us; speedup 1.0000x reference)
//
#include <hip/hip_runtime.h>
#include <hip/hip_bf16.h>

typedef unsigned short u16;
typedef __attribute__((ext_vector_type(8))) short b16x8;   // 8 bf16 = 4 VGPRs (MFMA A/B frag)
typedef __attribute__((ext_vector_type(4))) float f32x4;   // MFMA C/D frag

__device__ __forceinline__ u16 f2bf(float f) {
    union { float f; unsigned int u; } v; v.f = f;
    unsigned int u = v.u;
    return (u16)((u + 0x7FFFu + ((u >> 16) & 1u)) >> 16);
}

// ---------------------------------------------------------------------------
// K0: pack weights transposed to [n][k] bf16 so MFMA B-frags read contiguous k
// ---------------------------------------------------------------------------
__global__ __launch_bounds__(256) void k_pack_w(const float* __restrict__ w0,
                                                const float* __restrict__ w1,
                                                const float* __restrict__ w2,
                                                const float* __restrict__ w3,
                                                u16* __restrict__ dstbase) {
    const float* src = (blockIdx.x == 0) ? w0 : (blockIdx.x == 1) ? w1
                     : (blockIdx.x == 2) ? w2 : w3;
    u16* dst = dstbase + blockIdx.x * 16384;
    for (int i = threadIdx.x; i < 16384; i += 256) {
        int k = i >> 7, n = i & 127;
        dst[n * 128 + k] = f2bf(src[i]);   // coalesced read, strided tiny write
    }
}

// ---------------------------------------------------------------------------
// K1: LayerNorm + QKV projection (bf16 MFMA), writes [l][t][128] window layout
//     grid (1536, 3): 64 tokens/block, blockIdx.y = tensor (0=q,1=k,2=v)
// ---------------------------------------------------------------------------
struct K1Args {
    const float* x[3];
    const float* lng[3];
    const float* lnb[3];
    const float* bias[3];
    u16* out[3];
};

__global__ __launch_bounds__(256) void k_ln_proj(K1Args a, const u16* __restrict__ wt) {
    __shared__ u16 sW[16384];   // W^T [n][k], XOR-swizzled 16B chunks
    __shared__ u16 sA[8192];    // 64 x 128 normalized bf16, XOR-swizzled
    const int tid = threadIdx.x;
    const int tensor = blockIdx.y;

    // stage W^T (32 KB), swizzle: chunk' = chunk ^ (n&7)
    const u16* wsrc = wt + tensor * 16384;
#pragma unroll
    for (int it = 0; it < 8; ++it) {
        int e = (it * 256 + tid) << 3;       // element index, multiple of 8
        int n = e >> 7, k0 = e & 127;
        b16x8 v = *(const b16x8*)(wsrc + e);
        *(b16x8*)(sW + n * 128 + (((k0 >> 3) ^ (n & 7)) << 3)) = v;
    }

    // LayerNorm: 4 lanes per token, 32 f32 each
    const int r = tid >> 2, sub = tid & 3;
    const long long tt = (long long)blockIdx.x * 64 + r;   // 0..98303 = l*384 + t
    const int l = (int)(tt / 384), ti = (int)(tt % 384);
    const int nn = ti >> 6, w = ti & 63;
    const float* rowp = a.x[tensor] + ((long long)(nn * 16384 + l * 64 + w)) * 128 + sub * 32;
    float v[32];
    float s = 0.f, s2 = 0.f;
#pragma unroll
    for (int j = 0; j < 32; j += 4) {
        float4 f = *(const float4*)(rowp + j);
        v[j] = f.x; v[j + 1] = f.y; v[j + 2] = f.z; v[j + 3] = f.w;
        s  += (f.x + f.y) + (f.z + f.w);
        s2 += (f.x * f.x + f.y * f.y) + (f.z * f.z + f.w * f.w);
    }
    s  += __shfl_xor(s, 1);  s  += __shfl_xor(s, 2);
    s2 += __shfl_xor(s2, 1); s2 += __shfl_xor(s2, 2);
    const float mean = s * (1.f / 128.f);
    const float rstd = rsqrtf(s2 * (1.f / 128.f) - mean * mean + 1e-5f);
    const float* gp = a.lng[tensor];
    const float* bbp = a.lnb[tensor];
#pragma unroll
    for (int j = 0; j < 32; j += 8) {
        int k0 = sub * 32 + j;
        b16x8 tv;
#pragma unroll
        for (int q = 0; q < 8; ++q) {
            int k = k0 + q;
            tv[q] = (short)f2bf((v[j + q] - mean) * rstd * gp[k] + bbp[k]);
        }
        *(b16x8*)(sA + r * 128 + (((k0 >> 3) ^ (r & 7)) << 3)) = tv;
    }
    __syncthreads();

    // MFMA: wave wv owns 16-row mtile; 4 ktiles x 8 ntiles
    const int wv = tid >> 6, lane = tid & 63, lr = lane & 15, lg = lane >> 4;
    f32x4 acc[8];
#pragma unroll
    for (int i = 0; i < 8; ++i) acc[i] = (f32x4){0.f, 0.f, 0.f, 0.f};
    const int rowA = wv * 16 + lr;
#pragma unroll
    for (int kt = 0; kt < 4; ++kt) {
        const int ch = lg + 4 * kt;
        b16x8 af = *(const b16x8*)(sA + rowA * 128 + ((ch ^ (rowA & 7)) << 3));
#pragma unroll
        for (int nt = 0; nt < 8; ++nt) {
            const int nc = nt * 16 + lr;
            b16x8 bf = *(const b16x8*)(sW + nc * 128 + ((ch ^ (nc & 7)) << 3));
            acc[nt] = __builtin_amdgcn_mfma_f32_16x16x32_bf16(af, bf, acc[nt], 0, 0, 0);
        }
    }
    // epilogue: +bias, q pre-scaled by dh^-0.5, bf16 store to [l][t][128]
    const float scale = (tensor == 0) ? 0.17677669529663687f : 1.0f;
    u16* outp = a.out[tensor];
    const float* biasp = a.bias[tensor];
    const long long ttb = (long long)blockIdx.x * 64 + wv * 16;
#pragma unroll
    for (int nt = 0; nt < 8; ++nt) {
        const int col = nt * 16 + lr;
        const float bb = biasp[col];
#pragma unroll
        for (int rg = 0; rg < 4; ++rg) {
            const long long trow = ttb + lg * 4 + rg;   // D row = 4*(lane>>4)+reg
            outp[trow * 128 + col] = f2bf((acc[nt][rg] + bb) * scale);
        }
    }
}

// ---------------------------------------------------------------------------
// K2: per-(window, head) attention. grid (256, 4), 4 waves, 6 qtiles/wave.
//     S = Q K^T in one MFMA per 16x16 tile (K-dim = 32 = dh).
// ---------------------------------------------------------------------------
__global__ __launch_bounds__(256) void k_attn(const u16* __restrict__ qh,
                                              const u16* __restrict__ kh,
                                              const u16* __restrict__ vh,
                                              u16* __restrict__ ah) {
    __shared__ u16 sK[384 * 40];        // [t][dh], rows padded 32->40 (bank spread)
    __shared__ u16 sVt[32 * 392];       // V^T [dh][t], rows padded 384->392
    __shared__ u16 sP[4 * 16 * 192];    // per-wave P half-buffer [q][t''], XOR-swizzled
    const int tid = threadIdx.x;
    const int l = blockIdx.x, h = blockIdx.y;
    const long long base = ((long long)l * 384) * 128 + h * 32;

    // stage K (row-major) and V (transposed)
#pragma unroll
    for (int it = 0; it < 6; ++it) {
        int idx = it * 256 + tid;                 // 0..1535
        int t = idx >> 2, c = (idx & 3) << 3;     // c = dh0 in {0,8,16,24}
        b16x8 kv = *(const b16x8*)(kh + base + (long long)t * 128 + c);
        *(b16x8*)(sK + t * 40 + c) = kv;
        b16x8 vv = *(const b16x8*)(vh + base + (long long)t * 128 + c);
#pragma unroll
        for (int q = 0; q < 8; ++q) sVt[(c + q) * 392 + t] = (u16)vv[q];
    }
    __syncthreads();

    const int wv = tid >> 6, lane = tid & 63, lr = lane & 15, lg = lane >> 4;
    u16* myP = sP + wv * 16 * 192;

    for (int qt = wv; qt < 24; qt += 4) {
        // Q A-frag straight from global (L2/L3-hot): row = qt*16+lr, k = lg*8
        b16x8 qf = *(const b16x8*)(qh + base + (long long)(qt * 16 + lr) * 128 + lg * 8);
        f32x4 sacc[24];
#pragma unroll
        for (int kt = 0; kt < 24; ++kt) {
            b16x8 kf = *(const b16x8*)(sK + (kt * 16 + lr) * 40 + lg * 8);
            sacc[kt] = __builtin_amdgcn_mfma_f32_16x16x32_bf16(
                qf, kf, (f32x4){0.f, 0.f, 0.f, 0.f}, 0, 0, 0);
        }
        // softmax: row q = 4*lg+rg lives in 16 lanes (lr) x 24 regs
        float sm[4];
#pragma unroll
        for (int rg = 0; rg < 4; ++rg) {
            float m = sacc[0][rg];
#pragma unroll
            for (int kt = 1; kt < 24; ++kt) m = fmaxf(m, sacc[kt][rg]);
            m = fmaxf(m, __shfl_xor(m, 1));
            m = fmaxf(m, __shfl_xor(m, 2));
            m = fmaxf(m, __shfl_xor(m, 4));
            m = fmaxf(m, __shfl_xor(m, 8));
            float ss = 0.f;
#pragma unroll
            for (int kt = 0; kt < 24; ++kt) {
                float e = __expf(sacc[kt][rg] - m);
                sacc[kt][rg] = e;
                ss += e;
            }
            ss += __shfl_xor(ss, 1); ss += __shfl_xor(ss, 2);
            ss += __shfl_xor(ss, 4); ss += __shfl_xor(ss, 8);
            sm[rg] = ss;   // row sum (normalize at epilogue: fewer divides)
        }
        // PV in two K-halves of 192 tokens through the per-wave P buffer
        f32x4 pacc[2];
        pacc[0] = (f32x4){0.f, 0.f, 0.f, 0.f};
        pacc[1] = (f32x4){0.f, 0.f, 0.f, 0.f};
#pragma unroll
        for (int half = 0; half < 2; ++half) {
#pragma unroll
            for (int kt = 0; kt < 12; ++kt) {
#pragma unroll
                for (int rg = 0; rg < 4; ++rg) {
                    int q = lg * 4 + rg;
                    int tl = kt * 16 + lr;                 // t'' in [0,192)
                    int ch = (tl >> 3) ^ (q & 7);          // XOR swizzle (low 3 bits)
                    myP[q * 192 + ch * 8 + (tl & 7)] = f2bf(sacc[half * 12 + kt][rg]);
                }
            }
            // same-wave write->read: compiler inserts lgkmcnt waits
#pragma unroll
            for (int k2 = 0; k2 < 6; ++k2) {
                int ch = (4 * k2 + lg) ^ (lr & 7);
                b16x8 pf = *(const b16x8*)(myP + lr * 192 + ch * 8);
#pragma unroll
                for (int nt = 0; nt < 2; ++nt) {
                    b16x8 vf = *(const b16x8*)(sVt + (nt * 16 + lr) * 392 +
                                               half * 192 + k2 * 32 + lg * 8);
                    pacc[nt] = __builtin_amdgcn_mfma_f32_16x16x32_bf16(pf, vf, pacc[nt], 0, 0, 0);
                }
            }
        }
        // epilogue: divide by row sum, store A to [l][t][h*32+dh]
#pragma unroll
        for (int nt = 0; nt < 2; ++nt) {
#pragma unroll
            for (int rg = 0; rg < 4; ++rg) {
                float aa = pacc[nt][rg] / sm[rg];
                long long trow = (long long)(qt * 16 + lg * 4 + rg);
                ah[base + trow * 128 + nt * 16 + lr] = f2bf(aa);
            }
        }
    }
}

// ---------------------------------------------------------------------------
// K3: z = a @ Wp + bp, then mean over n — folded into the MFMA accumulator:
//     wave wv takes mtiles wv+4n (n=0..5) which all map to w-rows [16wv,16wv+16)
// ---------------------------------------------------------------------------
__global__ __launch_bounds__(256) void k_proj_mean(const u16* __restrict__ ah,
                                                   const u16* __restrict__ wtp,
                                                   const float* __restrict__ bp,
                                                   float* __restrict__ out) {
    __shared__ u16 sW[16384];
    const int tid = threadIdx.x;
    const int l = blockIdx.x;
#pragma unroll
    for (int it = 0; it < 8; ++it) {
        int e = (it * 256 + tid) << 3;
        int n = e >> 7, k0 = e & 127;
        b16x8 v = *(const b16x8*)(wtp + e);
        *(b16x8*)(sW + n * 128 + (((k0 >> 3) ^ (n & 7)) << 3)) = v;
    }
    __syncthreads();
    const int wv = tid >> 6, lane = tid & 63, lr = lane & 15, lg = lane >> 4;
    f32x4 acc[8];
#pragma unroll
    for (int i = 0; i < 8; ++i) acc[i] = (f32x4){0.f, 0.f, 0.f, 0.f};
#pragma unroll
    for (int nn = 0; nn < 6; ++nn) {
        const int mt = wv + nn * 4;   // t in [16mt,16mt+16): w = 16wv+row, n = nn
        const long long rowb = ((long long)l * 384 + mt * 16 + lr) * 128;
#pragma unroll
        for (int kt = 0; kt < 4; ++kt) {
            b16x8 af = *(const b16x8*)(ah + rowb + kt * 32 + lg * 8);
            const int ch = lg + 4 * kt;
#pragma unroll
            for (int nt = 0; nt < 8; ++nt) {
                const int nc = nt * 16 + lr;
                b16x8 bf = *(const b16x8*)(sW + nc * 128 + ((ch ^ (nc & 7)) << 3));
                acc[nt] = __builtin_amdgcn_mfma_f32_16x16x32_bf16(af, bf, acc[nt], 0, 0, 0);
            }
        }
    }
#pragma unroll
    for (int nt = 0; nt < 8; ++nt) {
        const int col = nt * 16 + lr;
        const float bb = bp[col];
#pragma unroll
        for (int rg = 0; rg < 4; ++rg) {
            const int wrow = wv * 16 + lg * 4 + rg;
            out[((long long)l * 64 + wrow) * 128 + col] = acc[nt][rg] * (1.0f / 6.0f) + bb;
        }
    }
}

// ---------------------------------------------------------------------------
extern "C" void kernel_launch(void* const* d_in, const int* in_sizes, int n_in,
                              void* d_out, int out_size, void* d_ws, size_t ws_size,
                              hipStream_t stream) {
    (void)in_sizes; (void)n_in; (void)out_size; (void)ws_size;
    const float* q      = (const float*)d_in[0];
    const float* k      = (const float*)d_in[1];
    const float* v      = (const float*)d_in[2];
    const float* ln_q_g = (const float*)d_in[3];
    const float* ln_q_b = (const float*)d_in[4];
    const float* ln_k_g = (const float*)d_in[5];
    const float* ln_k_b = (const float*)d_in[6];
    const float* ln_v_g = (const float*)d_in[7];
    const float* ln_v_b = (const float*)d_in[8];
    const float* Wq     = (const float*)d_in[9];
    const float* bq     = (const float*)d_in[10];
    const float* Wk     = (const float*)d_in[11];
    const float* bk     = (const float*)d_in[12];
    const float* Wv     = (const float*)d_in[13];
    const float* bv     = (const float*)d_in[14];
    const float* Wp     = (const float*)d_in[15];
    const float* bp     = (const float*)d_in[16];
    float* out = (float*)d_out;

    u16* ws = (u16*)d_ws;
    const long long MATE = 98304LL * 128;   // 12,582,912 elems per intermediate
    u16* wQ  = ws;
    u16* wK  = ws + MATE;
    u16* wV  = ws + 2 * MATE;
    u16* wA  = ws + 3 * MATE;
    u16* wWt = ws + 4 * MATE;               // 4 x 16384 packed transposed weights

    k_pack_w<<<4, 256, 0, stream>>>(Wq, Wk, Wv, Wp, wWt);

    K1Args args;
    args.x[0] = q;       args.x[1] = k;       args.x[2] = v;
    args.lng[0] = ln_q_g; args.lng[1] = ln_k_g; args.lng[2] = ln_v_g;
    args.lnb[0] = ln_q_b; args.lnb[1] = ln_k_b; args.lnb[2] = ln_v_b;
    args.bias[0] = bq;   args.bias[1] = bk;   args.bias[2] = bv;
    args.out[0] = wQ;    args.out[1] = wK;    args.out[2] = wV;
    k_ln_proj<<<dim3(1536, 3), 256, 0, stream>>>(args, wWt);

    k_attn<<<dim3(256, 4), 256, 0, stream>>>(wQ, wK, wV, wA);

    k_proj_mean<<<256, 256, 0, stream>>>(wA, wWt + 3 * 16384, bp, out);
}